// Round 12
// baseline (106.007 us; speedup 1.0000x reference)
//
#include <hip/hip_runtime.h>
#include <hip/hip_bf16.h>
#include <hip/hip_fp16.h>

typedef __attribute__((ext_vector_type(8))) short short8;
typedef __attribute__((ext_vector_type(4))) short short4v;
typedef __attribute__((ext_vector_type(4))) float f32x4;

#define B_ROWS 8192
#define HDIM 512
#define NDIM 1024
#define MDIM 128

__device__ __forceinline__ float softplusf(float z) {
  return fmaxf(z, 0.f) + log1pf(__expf(-fabsf(z)));
}
__device__ __forceinline__ unsigned short f2bfu(float f) {
  __hip_bfloat16 h = __float2bfloat16(f);   // round-to-nearest-even
  return *reinterpret_cast<unsigned short*>(&h);
}
__device__ __forceinline__ short8 pack8(float4 a, float4 b) {
  short8 r;
  r[0] = (short)f2bfu(a.x); r[1] = (short)f2bfu(a.y);
  r[2] = (short)f2bfu(a.z); r[3] = (short)f2bfu(a.w);
  r[4] = (short)f2bfu(b.x); r[5] = (short)f2bfu(b.y);
  r[6] = (short)f2bfu(b.z); r[7] = (short)f2bfu(b.w);
  return r;
}
__device__ __forceinline__ int pad(int i) { return i + (i >> 4); }

// ---------------------------------------------------------------------------
// Merged prologue: mem prep (blocks 0..511), scalars + x-pack (512..2559),
// Ws/Wk pack (2560..2703).
// ---------------------------------------------------------------------------
__global__ __launch_bounds__(256) void prep_all(
    const float* __restrict__ x, const float* __restrict__ Ws,
    const float* __restrict__ Wk, const float* __restrict__ mem,
    const float* __restrict__ Wb, const float* __restrict__ bb,
    const float* __restrict__ Wg, const float* __restrict__ bg,
    const float* __restrict__ Wgam, const float* __restrict__ bgam,
    short* __restrict__ xb, short* __restrict__ wsb, short* __restrict__ wkb,
    short* __restrict__ mn_bf, short* __restrict__ memT_bf,
    float* __restrict__ bgg)
{
  const int blk = blockIdx.x, t = threadIdx.x;
  if (blk < 512) {
    __shared__ float sredp[4];
    const int half = t >> 7, tl = t & 127;
    const int n = blk * 2 + half;
    const int wid = t >> 6;
    const float v = mem[n * MDIM + tl];
    float ss = v * v;
#pragma unroll
    for (int o = 32; o; o >>= 1) ss += __shfl_xor(ss, o);
    if ((t & 63) == 0) sredp[wid] = ss;
    __syncthreads();
    const float inv = 1.f / fmaxf(sqrtf(sredp[half * 2] + sredp[half * 2 + 1]), 1e-8f);
    mn_bf[n * MDIM + tl] = (short)f2bfu(v * inv);
    memT_bf[(size_t)tl * NDIM + n] = (short)f2bfu(v);
  } else if (blk < 2560) {
    const int wid = t >> 6, lane = t & 63;
    const int b = (blk - 512) * 4 + wid;
    const size_t xo = (size_t)b * HDIM + lane * 8;
    const float4 x0 = *(const float4*)(x + xo);
    const float4 x1 = *(const float4*)(x + xo + 4);
    *(short8*)(xb + xo) = pack8(x0, x1);
    const float4 b0 = *(const float4*)(Wb + lane * 8);
    const float4 b1 = *(const float4*)(Wb + lane * 8 + 4);
    const float4 g0 = *(const float4*)(Wg + lane * 8);
    const float4 g1 = *(const float4*)(Wg + lane * 8 + 4);
    const float4 m0 = *(const float4*)(Wgam + lane * 8);
    const float4 m1 = *(const float4*)(Wgam + lane * 8 + 4);
    float zb = x0.x*b0.x + x0.y*b0.y + x0.z*b0.z + x0.w*b0.w
             + x1.x*b1.x + x1.y*b1.y + x1.z*b1.z + x1.w*b1.w;
    float zg = x0.x*g0.x + x0.y*g0.y + x0.z*g0.z + x0.w*g0.w
             + x1.x*g1.x + x1.y*g1.y + x1.z*g1.z + x1.w*g1.w;
    float zm = x0.x*m0.x + x0.y*m0.y + x0.z*m0.z + x0.w*m0.w
             + x1.x*m1.x + x1.y*m1.y + x1.z*m1.z + x1.w*m1.w;
#pragma unroll
    for (int o = 32; o; o >>= 1) {
      zb += __shfl_xor(zb, o); zg += __shfl_xor(zg, o); zm += __shfl_xor(zm, o);
    }
    if (lane == 0) {
      zb += bb[0]; zg += bg[0]; zm += bgam[0];
      bgg[b * 4 + 0] = softplusf(zb);
      bgg[b * 4 + 1] = 1.f / (1.f + __expf(-zg));
      bgg[b * 4 + 2] = 1.f + softplusf(zm);
    }
  } else {
    const int NS4 = NDIM * HDIM / 4;
    const int NK4 = MDIM * HDIM / 4;
    const int stride = 144 * 256;
    for (int i = (blk - 2560) * 256 + t; i < NS4 + NK4; i += stride) {
      const float* src; short* dst; int j = i;
      if (j < NS4) { src = Ws; dst = wsb; }
      else { j -= NS4; src = Wk; dst = wkb; }
      const float4 v = ((const float4*)src)[j];
      short4v o;
      o[0] = (short)f2bfu(v.x); o[1] = (short)f2bfu(v.y);
      o[2] = (short)f2bfu(v.z); o[3] = (short)f2bfu(v.w);
      ((short4v*)dst)[j] = o;
    }
  }
}

// ---------------------------------------------------------------------------
// heads: blocks 0..255 -> fused k-head (khat in LDS, cos = khat@mn^T, fp16,
//        16 chunks of 64 cols so LDS stays under 40KB -> 4 blocks/CU);
//        blocks 256..767 -> slog = x Ws^T + bs (128x128 tile, fp16 out).
// ---------------------------------------------------------------------------
__global__ __launch_bounds__(256) void heads(
    const short* __restrict__ xb, const short* __restrict__ wkb,
    const float* __restrict__ bk, const short* __restrict__ mn_bf,
    __half* __restrict__ cosbH,
    const short* __restrict__ wsb, const float* __restrict__ bs,
    __half* __restrict__ slogH)
{
  __shared__ __align__(16) char smem[39680];
  const int tid = threadIdx.x, lane = tid & 63, wid = tid >> 6;
  const int fr = lane & 15, kg = (lane >> 4) << 3;

  if (blockIdx.x < 256) {
    // ---------------- cos branch ----------------
    short (*sA)[40]     = (short(*)[40])(smem);           // 32x40   = 2560 B
    short (*sW)[40]     = (short(*)[40])(smem + 2560);    // 128x40  = 10240 B
    short (*skhat)[136] = (short(*)[136])(smem + 12800);  // 32x136  = 8704 B
    short (*sMN)[136]   = (short(*)[136])(smem + 21504);  // 64x136  = 17408 B
    float (*snorm)[32]  = (float(*)[32])(smem + 38912);   // 4x32    = 512 B
    float* sinv         = (float*)(smem + 39424);         // 32      = 128 B

    const int bm = blockIdx.x;
    const int rbase = (lane >> 4) << 2;

    // phase 1: z[32][128] = x Wk^T
    f32x4 acc[2][2] = {};
    for (int k0 = 0; k0 < HDIM; k0 += 32) {
      if (k0) __syncthreads();
      if (tid < 128) {
        const int row = tid >> 2, c0 = (tid & 3) * 8;
        *(short8*)(&sA[row][c0]) =
            *(const short8*)(xb + (size_t)(bm * 32 + row) * HDIM + k0 + c0);
      }
#pragma unroll
      for (int u = tid; u < 512; u += 256) {
        const int row = u >> 2, c0 = (u & 3) * 8;
        *(short8*)(&sW[row][c0]) =
            *(const short8*)(wkb + (size_t)row * HDIM + k0 + c0);
      }
      __syncthreads();

      short8 af[2], bf[2];
#pragma unroll
      for (int i = 0; i < 2; i++) af[i] = *(const short8*)(&sA[i * 16 + fr][kg]);
#pragma unroll
      for (int n = 0; n < 2; n++) bf[n] = *(const short8*)(&sW[wid * 32 + n * 16 + fr][kg]);
#pragma unroll
      for (int i = 0; i < 2; i++)
#pragma unroll
        for (int n = 0; n < 2; n++)
          acc[i][n] = __builtin_amdgcn_mfma_f32_16x16x32_bf16(af[i], bf[n], acc[i][n], 0, 0, 0);
    }

    // phase 2: bias, row-norm, khat -> LDS (bf16)
    float z[2][2][4];
#pragma unroll
    for (int i = 0; i < 2; i++)
#pragma unroll
      for (int n = 0; n < 2; n++) {
        const float bv = bk[wid * 32 + n * 16 + fr];
#pragma unroll
        for (int r = 0; r < 4; r++) z[i][n][r] = acc[i][n][r] + bv;
      }
#pragma unroll
    for (int i = 0; i < 2; i++)
#pragma unroll
      for (int r = 0; r < 4; r++) {
        float sq = z[i][0][r] * z[i][0][r] + z[i][1][r] * z[i][1][r];
        sq += __shfl_xor(sq, 1); sq += __shfl_xor(sq, 2);
        sq += __shfl_xor(sq, 4); sq += __shfl_xor(sq, 8);
        if (fr == 0) snorm[wid][i * 16 + rbase + r] = sq;
      }
    __syncthreads();
    if (tid < 32) {
      const float nn = snorm[0][tid] + snorm[1][tid] + snorm[2][tid] + snorm[3][tid];
      sinv[tid] = 1.f / fmaxf(sqrtf(nn), 1e-8f);
    }
    __syncthreads();
#pragma unroll
    for (int i = 0; i < 2; i++)
#pragma unroll
      for (int n = 0; n < 2; n++)
#pragma unroll
        for (int r = 0; r < 4; r++) {
          const int row = i * 16 + rbase + r;
          skhat[row][wid * 32 + n * 16 + fr] = (short)f2bfu(z[i][n][r] * sinv[row]);
        }

    // phase 3: cos = khat @ mn^T, 16 chunks of 64 cols
    for (int cc = 0; cc < 16; cc++) {
#pragma unroll
      for (int i = 0; i < 4; i++) {
        const int u = tid + i * 256;           // 0..1023
        const int r = u >> 4, c0 = (u & 15) * 8;
        *(short8*)(&sMN[r][c0]) =
            *(const short8*)(mn_bf + (size_t)(cc * 64 + r) * MDIM + c0);
      }
      __syncthreads();   // sMN staged; also covers skhat writes on cc==0

      f32x4 acc2[2] = {};
#pragma unroll
      for (int k0 = 0; k0 < 128; k0 += 32) {
        short8 af2[2], bf2;
#pragma unroll
        for (int i = 0; i < 2; i++)
          af2[i] = *(const short8*)(&skhat[i * 16 + fr][k0 + kg]);
        bf2 = *(const short8*)(&sMN[wid * 16 + fr][k0 + kg]);
#pragma unroll
        for (int i = 0; i < 2; i++)
          acc2[i] = __builtin_amdgcn_mfma_f32_16x16x32_bf16(af2[i], bf2, acc2[i], 0, 0, 0);
      }
      __syncthreads();   // done reading sMN before next stage

#pragma unroll
      for (int i = 0; i < 2; i++)
#pragma unroll
        for (int r = 0; r < 4; r++) {
          const int row = i * 16 + rbase + r;
          const int gc = cc * 64 + wid * 16 + fr;
          cosbH[(size_t)(bm * 32 + row) * NDIM + gc] = __float2half(acc2[i][r]);
        }
    }
  } else {
    // ---------------- slog branch (128x128 tile, K=512) ----------------
    short* sA = (short*)smem;            // 128*32*2 = 8192 B
    short* sB = (short*)(smem + 8192);   // 8192 B
    const int blk2 = blockIdx.x - 256;
    const int bm = blk2 >> 3, bn = blk2 & 7;
    const int wr = wid >> 1, wc = wid & 1;

    f32x4 acc[4][4] = {};
    for (int k0 = 0; k0 < HDIM; k0 += 32) {
      if (k0) __syncthreads();
#pragma unroll
      for (int j = 0; j < 2; j++) {
        const int c = tid + j * 256;
        const short* g = xb + (size_t)(bm * 128 + (c >> 2)) * HDIM + k0 + (c & 3) * 8;
        short* l = sA + (j * 256 + wid * 64) * 8;
        __builtin_amdgcn_global_load_lds(
            (const __attribute__((address_space(1))) void*)g,
            (__attribute__((address_space(3))) void*)l, 16, 0, 0);
      }
#pragma unroll
      for (int j = 0; j < 2; j++) {
        const int c = tid + j * 256;
        const short* g = wsb + (size_t)(bn * 128 + (c >> 2)) * HDIM + k0 + (c & 3) * 8;
        short* l = sB + (j * 256 + wid * 64) * 8;
        __builtin_amdgcn_global_load_lds(
            (const __attribute__((address_space(1))) void*)g,
            (__attribute__((address_space(3))) void*)l, 16, 0, 0);
      }
      __syncthreads();

      short8 af[4], bf[4];
#pragma unroll
      for (int m = 0; m < 4; m++)
        af[m] = *(const short8*)(&sA[(wr * 64 + m * 16 + fr) * 32 + kg]);
#pragma unroll
      for (int n = 0; n < 4; n++)
        bf[n] = *(const short8*)(&sB[(wc * 64 + n * 16 + fr) * 32 + kg]);
#pragma unroll
      for (int m = 0; m < 4; m++)
#pragma unroll
        for (int n = 0; n < 4; n++)
          acc[m][n] = __builtin_amdgcn_mfma_f32_16x16x32_bf16(af[m], bf[n], acc[m][n], 0, 0, 0);
    }

#pragma unroll
    for (int m = 0; m < 4; m++)
#pragma unroll
      for (int n = 0; n < 4; n++) {
        const int gr = bm * 128 + wr * 64 + m * 16 + ((lane >> 4) << 2);
        const int gc = bn * 128 + wc * 64 + n * 16 + fr;
        const float bv = bs[gc];
#pragma unroll
        for (int r = 0; r < 4; r++)
          slogH[(size_t)(gr + r) * NDIM + gc] = __float2half(acc[m][n][r] + bv);
      }
  }
}

// ---------------------------------------------------------------------------
// 128x128-tile GEMM, bf16 in via global_load_lds, fp32 out, split-K.
// ---------------------------------------------------------------------------
__global__ __launch_bounds__(256) void kgemm_read(
    const short* __restrict__ A, const short* __restrict__ W,
    float* __restrict__ C, int ncols, int Kld, int ksplit, size_t cstride)
{
  __shared__ __align__(16) short sA[128 * 32];
  __shared__ __align__(16) short sB[128 * 32];

  const int tid = threadIdx.x, lane = tid & 63, wid = tid >> 6;
  const int bm = blockIdx.y, bn = blockIdx.x;
  const int wr = wid >> 1, wc = wid & 1;
  const int fr = lane & 15, kg = (lane >> 4) << 3;
  const int kbeg = blockIdx.z * ksplit, kend = kbeg + ksplit;

  f32x4 acc[4][4] = {};

  for (int k0 = kbeg; k0 < kend; k0 += 32) {
    if (k0 != kbeg) __syncthreads();
#pragma unroll
    for (int j = 0; j < 2; j++) {
      const int c = tid + j * 256;
      const short* g = A + (size_t)(bm * 128 + (c >> 2)) * Kld + k0 + (c & 3) * 8;
      short* l = &sA[(j * 256 + wid * 64) * 8];
      __builtin_amdgcn_global_load_lds(
          (const __attribute__((address_space(1))) void*)g,
          (__attribute__((address_space(3))) void*)l, 16, 0, 0);
    }
#pragma unroll
    for (int j = 0; j < 2; j++) {
      const int c = tid + j * 256;
      const short* g = W + (size_t)(bn * 128 + (c >> 2)) * Kld + k0 + (c & 3) * 8;
      short* l = &sB[(j * 256 + wid * 64) * 8];
      __builtin_amdgcn_global_load_lds(
          (const __attribute__((address_space(1))) void*)g,
          (__attribute__((address_space(3))) void*)l, 16, 0, 0);
    }
    __syncthreads();

    short8 af[4], bf[4];
#pragma unroll
    for (int m = 0; m < 4; m++)
      af[m] = *(const short8*)(&sA[(wr * 64 + m * 16 + fr) * 32 + kg]);
#pragma unroll
    for (int n = 0; n < 4; n++)
      bf[n] = *(const short8*)(&sB[(wc * 64 + n * 16 + fr) * 32 + kg]);

#pragma unroll
    for (int m = 0; m < 4; m++)
#pragma unroll
      for (int n = 0; n < 4; n++)
        acc[m][n] = __builtin_amdgcn_mfma_f32_16x16x32_bf16(af[m], bf[n], acc[m][n], 0, 0, 0);
  }

#pragma unroll
  for (int m = 0; m < 4; m++)
#pragma unroll
    for (int n = 0; n < 4; n++) {
      const int gr = bm * 128 + wr * 64 + m * 16 + ((lane >> 4) << 2);
      const int gc = bn * 128 + wc * 64 + n * 16 + fr;
#pragma unroll
      for (int r = 0; r < 4; r++)
        C[(size_t)(gr + r) * ncols + gc + blockIdx.z * cstride] = acc[m][n][r];
    }
}

// ---------------------------------------------------------------------------
// Sum 4 split-K partials into the output.  1M floats.
// ---------------------------------------------------------------------------
__global__ __launch_bounds__(256) void reduce4(const float* __restrict__ p,
                                               float* __restrict__ out)
{
  const int i = blockIdx.x * 256 + threadIdx.x;      // float4 index
  const float4* p4 = (const float4*)p;
  const float4 a = p4[i], b = p4[i + 262144], c = p4[i + 524288], d = p4[i + 786432];
  ((float4*)out)[i] = make_float4(a.x + b.x + c.x + d.x, a.y + b.y + c.y + d.y,
                                  a.z + b.z + c.z + d.z, a.w + b.w + c.w + d.w);
}

// ---------------------------------------------------------------------------
// FFT pieces (computed twiddles — round-7/9 validated). ANG0 = -2*pi/1024.
// ---------------------------------------------------------------------------
#define ANG0 (-0.0061359231515425650f)

template<int ST>
__device__ __forceinline__ void fft_mid(const float* __restrict__ sr,
                                        const float* __restrict__ si,
                                        float* __restrict__ dr,
                                        float* __restrict__ di, int tid,
                                        int j0, int j1, int j2, int j3)
{
  const int ls = 2 * ST, s = 1 << ls;
  const int p = tid >> ls, q = tid & (s - 1), tb = tid & ~(s - 1);
  const float a0r = sr[j0], a0i = si[j0], a1r = sr[j1], a1i = si[j1];
  const float a2r = sr[j2], a2i = si[j2], a3r = sr[j3], a3i = si[j3];
  const float b0r = a0r + a2r, b0i = a0i + a2i, b1r = a1r + a3r, b1i = a1i + a3i;
  const float b2r = a0r - a2r, b2i = a0i - a2i, b3r = a1r - a3r, b3i = a1i - a3i;
  const float A0r = b0r + b1r, A0i = b0i + b1i;
  const float A1r = b2r + b3i, A1i = b2i - b3r;
  const float A2r = b0r - b1r, A2i = b0i - b1i;
  const float A3r = b2r - b3i, A3i = b2i + b3r;
  const int o = q + 4 * s * p;
  dr[pad(o)] = A0r; di[pad(o)] = A0i;
  if constexpr (ST < 4) {
    float s1, c1; __sincosf(ANG0 * (float)tb, &s1, &c1);
    const float c2 = c1 * c1 - s1 * s1, s2 = 2.f * s1 * c1;
    const float c3 = c1 * c2 - s1 * s2, s3 = s1 * c2 + c1 * s2;
    dr[pad(o + s)]     = A1r * c1 - A1i * s1; di[pad(o + s)]     = A1r * s1 + A1i * c1;
    dr[pad(o + 2 * s)] = A2r * c2 - A2i * s2; di[pad(o + 2 * s)] = A2r * s2 + A2i * c2;
    dr[pad(o + 3 * s)] = A3r * c3 - A3i * s3; di[pad(o + 3 * s)] = A3r * s3 + A3i * c3;
  } else {
    dr[pad(o + s)]     = A1r; di[pad(o + s)]     = A1i;
    dr[pad(o + 2 * s)] = A2r; di[pad(o + 2 * s)] = A2i;
    dr[pad(o + 3 * s)] = A3r; di[pad(o + 3 * s)] = A3i;
  }
  __syncthreads();
}

// Half-width radix-4 stage of the 512-pt FFT (threads 0..127 active).
template<int J>
__device__ __forceinline__ void fft512_mid(const float* __restrict__ sr,
                                           const float* __restrict__ si,
                                           float* __restrict__ dr,
                                           float* __restrict__ di, int tid)
{
  if (tid < 128) {
    constexpr int s  = (J == 1) ? 2 : (J == 2) ? 8 : 32;
    constexpr int ns = (J == 1) ? 256 : (J == 2) ? 64 : 16;
    constexpr int ls = (J == 1) ? 1 : (J == 2) ? 3 : 5;
    const int p = tid >> ls, q = tid & (s - 1);
    const float a0r = sr[pad(tid)],       a0i = si[pad(tid)];
    const float a1r = sr[pad(tid + 128)], a1i = si[pad(tid + 128)];
    const float a2r = sr[pad(tid + 256)], a2i = si[pad(tid + 256)];
    const float a3r = sr[pad(tid + 384)], a3i = si[pad(tid + 384)];
    const float b0r = a0r + a2r, b0i = a0i + a2i, b1r = a1r + a3r, b1i = a1i + a3i;
    const float b2r = a0r - a2r, b2i = a0i - a2i, b3r = a1r - a3r, b3i = a1i - a3i;
    const float A0r = b0r + b1r, A0i = b0i + b1i;
    const float A1r = b2r + b3i, A1i = b2i - b3r;
    const float A2r = b0r - b1r, A2i = b0i - b1i;
    const float A3r = b2r - b3i, A3i = b2i + b3r;
    float s1, c1; __sincosf((-6.283185307179586f / (float)ns) * (float)p, &s1, &c1);
    const float c2 = c1 * c1 - s1 * s1, s2 = 2.f * s1 * c1;
    const float c3 = c1 * c2 - s1 * s2, s3 = s1 * c2 + c1 * s2;
    const int o = q + 4 * s * p;
    dr[pad(o)]         = A0r;                 di[pad(o)]         = A0i;
    dr[pad(o + s)]     = A1r * c1 - A1i * s1; di[pad(o + s)]     = A1r * s1 + A1i * c1;
    dr[pad(o + 2 * s)] = A2r * c2 - A2i * s2; di[pad(o + 2 * s)] = A2r * s2 + A2i * c2;
    dr[pad(o + 3 * s)] = A3r * c3 - A3i * s3; di[pad(o + 3 * s)] = A3r * s3 + A3i * c3;
  }
  __syncthreads();
}

// ---------------------------------------------------------------------------
// Row pass (1-row/block, round-9 validated): softmaxes, gate, FFT1 (1024),
// Hermitian product, irfft via 512, sharpen, normalize.
// ---------------------------------------------------------------------------
__global__ __launch_bounds__(256) void rowpass(
    const __half* __restrict__ slogH, const __half* __restrict__ cosbH,
    const float* __restrict__ bgg, const float* __restrict__ prev,
    float* __restrict__ wout, short* __restrict__ wbf)
{
  __shared__ float bAr[1088], bAi[1088], bBr[1088], bBi[1088];
  __shared__ float sred[8];
  const int b = blockIdx.x, tid = threadIdx.x;
  const int lane = tid & 63, wid = tid >> 6;
  const int j0 = pad(tid), j1 = pad(tid + 256), j2 = pad(tid + 512), j3 = pad(tid + 768);

  const float beta = bgg[b * 4 + 0], g = bgg[b * 4 + 1], gamma = bgg[b * 4 + 2];

  float sv[4], cv[4];
  float e1 = 0.f, e2 = 0.f;
#pragma unroll
  for (int i = 0; i < 4; i++) {
    sv[i] = __expf(__half2float(slogH[(size_t)b * NDIM + tid + i * 256]));
    cv[i] = __expf(beta * __half2float(cosbH[(size_t)b * NDIM + tid + i * 256]));
    e1 += sv[i]; e2 += cv[i];
  }
#pragma unroll
  for (int o = 32; o; o >>= 1) { e1 += __shfl_xor(e1, o); e2 += __shfl_xor(e2, o); }
  if (lane == 0) { sred[wid * 2] = e1; sred[wid * 2 + 1] = e2; }
  __syncthreads();
  const float r1 = 1.f / (sred[0] + sred[2] + sred[4] + sred[6]);
  const float r2 = 1.f / (sred[1] + sred[3] + sred[5] + sred[7]);

  float s1, c1; __sincosf(ANG0 * (float)tid, &s1, &c1);
  const float c2 = c1 * c1 - s1 * s1, s2 = 2.f * s1 * c1;
  const float c3 = c1 * c2 - s1 * s2, s3 = s1 * c2 + c1 * s2;

  // ---- pack + stage 0 of FFT1 in registers -> B ----
  {
    float ar[4], ai[4];
#pragma unroll
    for (int i = 0; i < 4; i++) {
      const int idx = tid + i * 256;
      const float pv = prev[(size_t)b * NDIM + idx];
      ar[i] = g * cv[i] * r2 + (1.f - g) * pv;   // w_g
      ai[i] = sv[i] * r1;                        // s
    }
    const float b0r = ar[0] + ar[2], b0i = ai[0] + ai[2];
    const float b1r = ar[1] + ar[3], b1i = ai[1] + ai[3];
    const float b2r = ar[0] - ar[2], b2i = ai[0] - ai[2];
    const float b3r = ar[1] - ar[3], b3i = ai[1] - ai[3];
    const float A0r = b0r + b1r, A0i = b0i + b1i;
    const float A1r = b2r + b3i, A1i = b2i - b3r;
    const float A2r = b0r - b1r, A2i = b0i - b1i;
    const float A3r = b2r - b3i, A3i = b2i + b3r;
    const int o4 = 4 * tid;
    bBr[pad(o4)]     = A0r;                  bBi[pad(o4)]     = A0i;
    bBr[pad(o4 + 1)] = A1r * c1 - A1i * s1;  bBi[pad(o4 + 1)] = A1r * s1 + A1i * c1;
    bBr[pad(o4 + 2)] = A2r * c2 - A2i * s2;  bBi[pad(o4 + 2)] = A2r * s2 + A2i * c2;
    bBr[pad(o4 + 3)] = A3r * c3 - A3i * s3;  bBi[pad(o4 + 3)] = A3r * s3 + A3i * c3;
  }
  __syncthreads();

  fft_mid<1>(bBr, bBi, bAr, bAi, tid, j0, j1, j2, j3);
  fft_mid<2>(bAr, bAi, bBr, bBi, tid, j0, j1, j2, j3);
  fft_mid<3>(bBr, bBi, bAr, bAi, tid, j0, j1, j2, j3);
  fft_mid<4>(bAr, bAi, bBr, bBi, tid, j0, j1, j2, j3);   // Z in B, natural order

  // ---- Hermitian product: P[k] = W[k]*S[k], k = 0..512 -> A ----
#pragma unroll
  for (int i = 0; i < 2; i++) {
    const int k = tid + i * 256;
    const int kp = pad(k), rp = pad((1024 - k) & 1023);
    const float Zkr = bBr[kp], Zki = bBi[kp];
    const float Zrr = bBr[rp], Zri = bBi[rp];
    const float Wr = 0.5f * (Zkr + Zrr), Wi = 0.5f * (Zki - Zri);
    const float Sr = 0.5f * (Zki + Zri), Si = 0.5f * (Zrr - Zkr);
    bAr[kp] = Wr * Sr - Wi * Si;
    bAi[kp] = Wr * Si + Wi * Sr;
  }
  if (tid == 0) {
    const int kp = pad(512);
    bAr[kp] = bBr[kp] * bBi[kp];   // W=Re(Z512), S=Im(Z512), both real
    bAi[kp] = 0.f;
  }
  __syncthreads();

  // ---- Q construction + conj + radix-2 register stage -> B (512 pts) ----
  {
    float es, ec; __sincosf(0.0061359231515425650f * (float)tid, &es, &ec);
    const float P0r = bAr[pad(tid)],        P0i = bAi[pad(tid)];
    const float Pa0r = bAr[pad(512 - tid)], Pa0i = bAi[pad(512 - tid)];
    const float S0r = P0r + Pa0r, S0i = P0i - Pa0i;
    const float D0r = P0r - Pa0r, D0i = P0i + Pa0i;
    const float Q0r = S0r - es * D0r - ec * D0i;
    const float Q0i = S0i + ec * D0r - es * D0i;
    const float P1r = bAr[pad(tid + 256)],  P1i = bAi[pad(tid + 256)];
    const float Pa1r = bAr[pad(256 - tid)], Pa1i = bAi[pad(256 - tid)];
    const float S1r = P1r + Pa1r, S1i = P1i - Pa1i;
    const float D1r = P1r - Pa1r, D1i = P1i + Pa1i;
    const float Q1r = S1r - ec * D1r + es * D1i;
    const float Q1i = S1i - es * D1r - ec * D1i;
    const float ur = Q0r, ui = -Q0i, vr = Q1r, vi = -Q1i;
    float ts, tc; __sincosf(-0.012271846303085130f * (float)tid, &ts, &tc);
    const float d_r = ur - vr, d_i = ui - vi;
    bBr[pad(2 * tid)]     = ur + vr;             bBi[pad(2 * tid)]     = ui + vi;
    bBr[pad(2 * tid + 1)] = d_r * tc - d_i * ts; bBi[pad(2 * tid + 1)] = d_r * ts + d_i * tc;
  }
  __syncthreads();

  fft512_mid<1>(bBr, bBi, bAr, bAi, tid);
  fft512_mid<2>(bAr, bAi, bBr, bBi, tid);
  fft512_mid<3>(bBr, bBi, bAr, bAi, tid);

  if (tid < 128) {
    const int i0 = pad(tid), i1 = pad(tid + 128), i2 = pad(tid + 256), i3 = pad(tid + 384);
    const float a0r = bAr[i0], a0i = bAi[i0], a1r = bAr[i1], a1i = bAi[i1];
    const float a2r = bAr[i2], a2i = bAi[i2], a3r = bAr[i3], a3i = bAi[i3];
    const float b0r = a0r + a2r, b0i = a0i + a2i, b1r = a1r + a3r, b1i = a1i + a3i;
    const float b2r = a0r - a2r, b2i = a0i - a2i, b3r = a1r - a3r, b3i = a1i - a3i;
    bBr[i0] = b0r + b1r; bBi[i0] = b0i + b1i;
    bBr[i1] = b2r + b3i; bBi[i1] = b2i - b3r;
    bBr[i2] = b0r - b1r; bBi[i2] = b0i - b1i;
    bBr[i3] = b2r - b3i; bBi[i3] = b2i + b3r;
  }
  __syncthreads();

  const int m0 = pad(2 * tid), m1 = pad(2 * tid + 1);
  float xv[4];
  xv[0] =  bBr[m0] * (1.f / 1024.f);
  xv[1] = -bBi[m0] * (1.f / 1024.f);
  xv[2] =  bBr[m1] * (1.f / 1024.f);
  xv[3] = -bBi[m1] * (1.f / 1024.f);

  float wt[4]; float esum = 0.f;
#pragma unroll
  for (int i = 0; i < 4; i++) {
    const float v = fmaxf(xv[i], 0.f);
    const float p = (v > 0.f) ? __expf(gamma * __logf(v)) : 0.f;
    wt[i] = p; esum += p;
  }
#pragma unroll
  for (int o = 32; o; o >>= 1) esum += __shfl_xor(esum, o);
  if (lane == 0) sred[wid] = esum;
  __syncthreads();
  const float rn = 1.f / (sred[0] + sred[1] + sred[2] + sred[3] + 1e-16f);
  const float w0 = wt[0] * rn, w1 = wt[1] * rn, w2 = wt[2] * rn, w3 = wt[3] * rn;
  *(float4*)(wout + (size_t)b * NDIM + 4 * tid) = make_float4(w0, w1, w2, w3);
  short4v wb;
  wb[0] = (short)f2bfu(w0); wb[1] = (short)f2bfu(w1);
  wb[2] = (short)f2bfu(w2); wb[3] = (short)f2bfu(w3);
  *(short4v*)(wbf + (size_t)b * NDIM + 4 * tid) = wb;
}

// ---------------------------------------------------------------------------
extern "C" void kernel_launch(void* const* d_in, const int* in_sizes, int n_in,
                              void* d_out, int out_size, void* d_ws, size_t ws_size,
                              hipStream_t stream)
{
  const float* x    = (const float*)d_in[0];
  const float* prev = (const float*)d_in[1];
  const float* mem  = (const float*)d_in[2];
  const float* Wk   = (const float*)d_in[3];
  const float* bk   = (const float*)d_in[4];
  const float* Wb   = (const float*)d_in[5];
  const float* bb   = (const float*)d_in[6];
  const float* Wg   = (const float*)d_in[7];
  const float* bg   = (const float*)d_in[8];
  const float* Ws   = (const float*)d_in[9];
  const float* bs   = (const float*)d_in[10];
  const float* Wgam = (const float*)d_in[11];
  const float* bgam = (const float*)d_in[12];

  char* ws = (char*)d_ws;
  short*  mn_bf   = (short*) (ws + 0);          //  256 KB
  short*  memT_bf = (short*) (ws + 262144);     //  256 KB
  float*  bgg     = (float*) (ws + 524288);     //  128 KB
  __half* slogH   = (__half*)(ws + 655360);     //   16 MB
  __half* cosbH   = (__half*)(ws + 17432576);   //   16 MB
  short*  xb      = (short*) (ws + 34209792);   //    8 MB
  short*  wsb     = (short*) (ws + 42598400);   //    1 MB
  short*  wkb     = (short*) (ws + 43646976);   //  128 KB
  short*  wbf     = (short*) (ws + 43778048);   //   16 MB
  float*  rpart   = (float*) (ws + 60555264);   //   16 MB (ends ~77.3 MB)

  float* readout = (float*)d_out;                  // [8192][128]
  float* wout = readout + (size_t)B_ROWS * MDIM;   // [8192][1024]

  prep_all<<<2704, 256, 0, stream>>>(x, Ws, Wk, mem, Wb, bb, Wg, bg, Wgam, bgam,
                                     xb, wsb, wkb, mn_bf, memT_bf, bgg);
  heads<<<768, 256, 0, stream>>>(xb, wkb, bk, mn_bf, cosbH, wsb, bs, slogH);
  rowpass<<<B_ROWS, 256, 0, stream>>>(slogH, cosbH, bgg, prev, wout, wbf);
  kgemm_read<<<dim3(1, B_ROWS / 128, 4), 256, 0, stream>>>(
      wbf, memT_bf, rpart, MDIM, NDIM, 256, (size_t)B_ROWS * MDIM);
  reduce4<<<1024, 256, 0, stream>>>(rpart, readout);
}

// Round 13
// 101.257 us; speedup vs baseline: 1.0469x; 1.0469x over previous
//
#include <hip/hip_runtime.h>
#include <hip/hip_bf16.h>
#include <hip/hip_fp16.h>

typedef __attribute__((ext_vector_type(8))) short short8;
typedef __attribute__((ext_vector_type(4))) short short4v;
typedef __attribute__((ext_vector_type(4))) float f32x4;

#define B_ROWS 8192
#define HDIM 512
#define NDIM 1024
#define MDIM 128

__device__ __forceinline__ float softplusf(float z) {
  return fmaxf(z, 0.f) + log1pf(__expf(-fabsf(z)));
}
__device__ __forceinline__ unsigned short f2bfu(float f) {
  __hip_bfloat16 h = __float2bfloat16(f);   // round-to-nearest-even
  return *reinterpret_cast<unsigned short*>(&h);
}
__device__ __forceinline__ short8 pack8(float4 a, float4 b) {
  short8 r;
  r[0] = (short)f2bfu(a.x); r[1] = (short)f2bfu(a.y);
  r[2] = (short)f2bfu(a.z); r[3] = (short)f2bfu(a.w);
  r[4] = (short)f2bfu(b.x); r[5] = (short)f2bfu(b.y);
  r[6] = (short)f2bfu(b.z); r[7] = (short)f2bfu(b.w);
  return r;
}
__device__ __forceinline__ int pad(int i) { return i + (i >> 4); }

// ---------------------------------------------------------------------------
// Merged prologue: mem prep (blocks 0..511), scalars + x-pack (512..2559),
// Ws/Wk pack (2560..2703).
// ---------------------------------------------------------------------------
__global__ __launch_bounds__(256) void prep_all(
    const float* __restrict__ x, const float* __restrict__ Ws,
    const float* __restrict__ Wk, const float* __restrict__ mem,
    const float* __restrict__ Wb, const float* __restrict__ bb,
    const float* __restrict__ Wg, const float* __restrict__ bg,
    const float* __restrict__ Wgam, const float* __restrict__ bgam,
    short* __restrict__ xb, short* __restrict__ wsb, short* __restrict__ wkb,
    short* __restrict__ mn_bf, short* __restrict__ memT_bf,
    float* __restrict__ bgg)
{
  const int blk = blockIdx.x, t = threadIdx.x;
  if (blk < 512) {
    __shared__ float sredp[4];
    const int half = t >> 7, tl = t & 127;
    const int n = blk * 2 + half;
    const int wid = t >> 6;
    const float v = mem[n * MDIM + tl];
    float ss = v * v;
#pragma unroll
    for (int o = 32; o; o >>= 1) ss += __shfl_xor(ss, o);
    if ((t & 63) == 0) sredp[wid] = ss;
    __syncthreads();
    const float inv = 1.f / fmaxf(sqrtf(sredp[half * 2] + sredp[half * 2 + 1]), 1e-8f);
    mn_bf[n * MDIM + tl] = (short)f2bfu(v * inv);
    memT_bf[(size_t)tl * NDIM + n] = (short)f2bfu(v);
  } else if (blk < 2560) {
    const int wid = t >> 6, lane = t & 63;
    const int b = (blk - 512) * 4 + wid;
    const size_t xo = (size_t)b * HDIM + lane * 8;
    const float4 x0 = *(const float4*)(x + xo);
    const float4 x1 = *(const float4*)(x + xo + 4);
    *(short8*)(xb + xo) = pack8(x0, x1);
    const float4 b0 = *(const float4*)(Wb + lane * 8);
    const float4 b1 = *(const float4*)(Wb + lane * 8 + 4);
    const float4 g0 = *(const float4*)(Wg + lane * 8);
    const float4 g1 = *(const float4*)(Wg + lane * 8 + 4);
    const float4 m0 = *(const float4*)(Wgam + lane * 8);
    const float4 m1 = *(const float4*)(Wgam + lane * 8 + 4);
    float zb = x0.x*b0.x + x0.y*b0.y + x0.z*b0.z + x0.w*b0.w
             + x1.x*b1.x + x1.y*b1.y + x1.z*b1.z + x1.w*b1.w;
    float zg = x0.x*g0.x + x0.y*g0.y + x0.z*g0.z + x0.w*g0.w
             + x1.x*g1.x + x1.y*g1.y + x1.z*g1.z + x1.w*g1.w;
    float zm = x0.x*m0.x + x0.y*m0.y + x0.z*m0.z + x0.w*m0.w
             + x1.x*m1.x + x1.y*m1.y + x1.z*m1.z + x1.w*m1.w;
#pragma unroll
    for (int o = 32; o; o >>= 1) {
      zb += __shfl_xor(zb, o); zg += __shfl_xor(zg, o); zm += __shfl_xor(zm, o);
    }
    if (lane == 0) {
      zb += bb[0]; zg += bg[0]; zm += bgam[0];
      bgg[b * 4 + 0] = softplusf(zb);
      bgg[b * 4 + 1] = 1.f / (1.f + __expf(-zg));
      bgg[b * 4 + 2] = 1.f + softplusf(zm);
    }
  } else {
    const int NS4 = NDIM * HDIM / 4;
    const int NK4 = MDIM * HDIM / 4;
    const int stride = 144 * 256;
    for (int i = (blk - 2560) * 256 + t; i < NS4 + NK4; i += stride) {
      const float* src; short* dst; int j = i;
      if (j < NS4) { src = Ws; dst = wsb; }
      else { j -= NS4; src = Wk; dst = wkb; }
      const float4 v = ((const float4*)src)[j];
      short4v o;
      o[0] = (short)f2bfu(v.x); o[1] = (short)f2bfu(v.y);
      o[2] = (short)f2bfu(v.z); o[3] = (short)f2bfu(v.w);
      ((short4v*)dst)[j] = o;
    }
  }
}

// ---------------------------------------------------------------------------
// heads (round-11 best config): blocks 0..255 -> fused k-head (khat in LDS,
// cos = khat@mn^T in 8 chunks of 128 cols, fp16 out); blocks 256..767 ->
// slog = x Ws^T + bs (128x128 tile, fp16 out).  57KB carve.
// ---------------------------------------------------------------------------
__global__ __launch_bounds__(256) void heads(
    const short* __restrict__ xb, const short* __restrict__ wkb,
    const float* __restrict__ bk, const short* __restrict__ mn_bf,
    __half* __restrict__ cosbH,
    const short* __restrict__ wsb, const float* __restrict__ bs,
    __half* __restrict__ slogH)
{
  __shared__ __align__(16) char smem[56960];
  const int tid = threadIdx.x, lane = tid & 63, wid = tid >> 6;
  const int fr = lane & 15, kg = (lane >> 4) << 3;

  if (blockIdx.x < 256) {
    // ---------------- cos branch ----------------
    short (*sA)[40]     = (short(*)[40])(smem);           // 32x40
    short (*sW)[40]     = (short(*)[40])(smem + 2560);    // 128x40
    short (*skhat)[136] = (short(*)[136])(smem + 12800);  // 32x136
    short (*sMN)[136]   = (short(*)[136])(smem + 21504);  // 128x136
    float (*snorm)[32]  = (float(*)[32])(smem + 56320);   // 4x32
    float* sinv         = (float*)(smem + 56832);         // 32

    const int bm = blockIdx.x;
    const int rbase = (lane >> 4) << 2;

    f32x4 acc[2][2] = {};
    for (int k0 = 0; k0 < HDIM; k0 += 32) {
      if (k0) __syncthreads();
      if (tid < 128) {
        const int row = tid >> 2, c0 = (tid & 3) * 8;
        *(short8*)(&sA[row][c0]) =
            *(const short8*)(xb + (size_t)(bm * 32 + row) * HDIM + k0 + c0);
      }
#pragma unroll
      for (int u = tid; u < 512; u += 256) {
        const int row = u >> 2, c0 = (u & 3) * 8;
        *(short8*)(&sW[row][c0]) =
            *(const short8*)(wkb + (size_t)row * HDIM + k0 + c0);
      }
      __syncthreads();

      short8 af[2], bf[2];
#pragma unroll
      for (int i = 0; i < 2; i++) af[i] = *(const short8*)(&sA[i * 16 + fr][kg]);
#pragma unroll
      for (int n = 0; n < 2; n++) bf[n] = *(const short8*)(&sW[wid * 32 + n * 16 + fr][kg]);
#pragma unroll
      for (int i = 0; i < 2; i++)
#pragma unroll
        for (int n = 0; n < 2; n++)
          acc[i][n] = __builtin_amdgcn_mfma_f32_16x16x32_bf16(af[i], bf[n], acc[i][n], 0, 0, 0);
    }

    float z[2][2][4];
#pragma unroll
    for (int i = 0; i < 2; i++)
#pragma unroll
      for (int n = 0; n < 2; n++) {
        const float bv = bk[wid * 32 + n * 16 + fr];
#pragma unroll
        for (int r = 0; r < 4; r++) z[i][n][r] = acc[i][n][r] + bv;
      }
#pragma unroll
    for (int i = 0; i < 2; i++)
#pragma unroll
      for (int r = 0; r < 4; r++) {
        float sq = z[i][0][r] * z[i][0][r] + z[i][1][r] * z[i][1][r];
        sq += __shfl_xor(sq, 1); sq += __shfl_xor(sq, 2);
        sq += __shfl_xor(sq, 4); sq += __shfl_xor(sq, 8);
        if (fr == 0) snorm[wid][i * 16 + rbase + r] = sq;
      }
    __syncthreads();
    if (tid < 32) {
      const float nn = snorm[0][tid] + snorm[1][tid] + snorm[2][tid] + snorm[3][tid];
      sinv[tid] = 1.f / fmaxf(sqrtf(nn), 1e-8f);
    }
    __syncthreads();
#pragma unroll
    for (int i = 0; i < 2; i++)
#pragma unroll
      for (int n = 0; n < 2; n++)
#pragma unroll
        for (int r = 0; r < 4; r++) {
          const int row = i * 16 + rbase + r;
          skhat[row][wid * 32 + n * 16 + fr] = (short)f2bfu(z[i][n][r] * sinv[row]);
        }

    for (int cc = 0; cc < 8; cc++) {
#pragma unroll
      for (int i = 0; i < 8; i++) {
        const int u = tid + i * 256;
        const int r = u >> 4, c0 = (u & 15) * 8;
        *(short8*)(&sMN[r][c0]) =
            *(const short8*)(mn_bf + (size_t)(cc * 128 + r) * MDIM + c0);
      }
      __syncthreads();   // sMN staged; also covers skhat writes on cc==0

      f32x4 acc2[2][2] = {};
#pragma unroll
      for (int k0 = 0; k0 < 128; k0 += 32) {
        short8 af2[2], bf2[2];
#pragma unroll
        for (int i = 0; i < 2; i++)
          af2[i] = *(const short8*)(&skhat[i * 16 + fr][k0 + kg]);
#pragma unroll
        for (int n = 0; n < 2; n++)
          bf2[n] = *(const short8*)(&sMN[wid * 32 + n * 16 + fr][k0 + kg]);
#pragma unroll
        for (int i = 0; i < 2; i++)
#pragma unroll
          for (int n = 0; n < 2; n++)
            acc2[i][n] = __builtin_amdgcn_mfma_f32_16x16x32_bf16(af2[i], bf2[n], acc2[i][n], 0, 0, 0);
      }
      __syncthreads();   // done reading sMN before next stage

#pragma unroll
      for (int i = 0; i < 2; i++)
#pragma unroll
        for (int n = 0; n < 2; n++)
#pragma unroll
          for (int r = 0; r < 4; r++) {
            const int row = i * 16 + rbase + r;
            const int gc = cc * 128 + wid * 32 + n * 16 + fr;
            cosbH[(size_t)(bm * 32 + row) * NDIM + gc] = __float2half(acc2[i][n][r]);
          }
    }
  } else {
    // ---------------- slog branch (128x128 tile, K=512) ----------------
    short* sA = (short*)smem;            // 128*32
    short* sB = (short*)(smem + 8192);
    const int blk2 = blockIdx.x - 256;
    const int bm = blk2 >> 3, bn = blk2 & 7;
    const int wr = wid >> 1, wc = wid & 1;

    f32x4 acc[4][4] = {};
    for (int k0 = 0; k0 < HDIM; k0 += 32) {
      if (k0) __syncthreads();
#pragma unroll
      for (int j = 0; j < 2; j++) {
        const int c = tid + j * 256;
        const short* g = xb + (size_t)(bm * 128 + (c >> 2)) * HDIM + k0 + (c & 3) * 8;
        short* l = sA + (j * 256 + wid * 64) * 8;
        __builtin_amdgcn_global_load_lds(
            (const __attribute__((address_space(1))) void*)g,
            (__attribute__((address_space(3))) void*)l, 16, 0, 0);
      }
#pragma unroll
      for (int j = 0; j < 2; j++) {
        const int c = tid + j * 256;
        const short* g = wsb + (size_t)(bn * 128 + (c >> 2)) * HDIM + k0 + (c & 3) * 8;
        short* l = sB + (j * 256 + wid * 64) * 8;
        __builtin_amdgcn_global_load_lds(
            (const __attribute__((address_space(1))) void*)g,
            (__attribute__((address_space(3))) void*)l, 16, 0, 0);
      }
      __syncthreads();

      short8 af[4], bf[4];
#pragma unroll
      for (int m = 0; m < 4; m++)
        af[m] = *(const short8*)(&sA[(wr * 64 + m * 16 + fr) * 32 + kg]);
#pragma unroll
      for (int n = 0; n < 4; n++)
        bf[n] = *(const short8*)(&sB[(wc * 64 + n * 16 + fr) * 32 + kg]);
#pragma unroll
      for (int m = 0; m < 4; m++)
#pragma unroll
        for (int n = 0; n < 4; n++)
          acc[m][n] = __builtin_amdgcn_mfma_f32_16x16x32_bf16(af[m], bf[n], acc[m][n], 0, 0, 0);
    }

#pragma unroll
    for (int m = 0; m < 4; m++)
#pragma unroll
      for (int n = 0; n < 4; n++) {
        const int gr = bm * 128 + wr * 64 + m * 16 + ((lane >> 4) << 2);
        const int gc = bn * 128 + wc * 64 + n * 16 + fr;
        const float bv = bs[gc];
#pragma unroll
        for (int r = 0; r < 4; r++)
          slogH[(size_t)(gr + r) * NDIM + gc] = __float2half(acc[m][n][r] + bv);
      }
  }
}

// ---------------------------------------------------------------------------
// 128x128-tile GEMM, bf16 in via global_load_lds, fp32 out, split-K.
// ---------------------------------------------------------------------------
__global__ __launch_bounds__(256) void kgemm_read(
    const short* __restrict__ A, const short* __restrict__ W,
    float* __restrict__ C, int ncols, int Kld, int ksplit, size_t cstride)
{
  __shared__ __align__(16) short sA[128 * 32];
  __shared__ __align__(16) short sB[128 * 32];

  const int tid = threadIdx.x, lane = tid & 63, wid = tid >> 6;
  const int bm = blockIdx.y, bn = blockIdx.x;
  const int wr = wid >> 1, wc = wid & 1;
  const int fr = lane & 15, kg = (lane >> 4) << 3;
  const int kbeg = blockIdx.z * ksplit, kend = kbeg + ksplit;

  f32x4 acc[4][4] = {};

  for (int k0 = kbeg; k0 < kend; k0 += 32) {
    if (k0 != kbeg) __syncthreads();
#pragma unroll
    for (int j = 0; j < 2; j++) {
      const int c = tid + j * 256;
      const short* g = A + (size_t)(bm * 128 + (c >> 2)) * Kld + k0 + (c & 3) * 8;
      short* l = &sA[(j * 256 + wid * 64) * 8];
      __builtin_amdgcn_global_load_lds(
          (const __attribute__((address_space(1))) void*)g,
          (__attribute__((address_space(3))) void*)l, 16, 0, 0);
    }
#pragma unroll
    for (int j = 0; j < 2; j++) {
      const int c = tid + j * 256;
      const short* g = W + (size_t)(bn * 128 + (c >> 2)) * Kld + k0 + (c & 3) * 8;
      short* l = &sB[(j * 256 + wid * 64) * 8];
      __builtin_amdgcn_global_load_lds(
          (const __attribute__((address_space(1))) void*)g,
          (__attribute__((address_space(3))) void*)l, 16, 0, 0);
    }
    __syncthreads();

    short8 af[4], bf[4];
#pragma unroll
    for (int m = 0; m < 4; m++)
      af[m] = *(const short8*)(&sA[(wr * 64 + m * 16 + fr) * 32 + kg]);
#pragma unroll
    for (int n = 0; n < 4; n++)
      bf[n] = *(const short8*)(&sB[(wc * 64 + n * 16 + fr) * 32 + kg]);

#pragma unroll
    for (int m = 0; m < 4; m++)
#pragma unroll
      for (int n = 0; n < 4; n++)
        acc[m][n] = __builtin_amdgcn_mfma_f32_16x16x32_bf16(af[m], bf[n], acc[m][n], 0, 0, 0);
  }

#pragma unroll
  for (int m = 0; m < 4; m++)
#pragma unroll
    for (int n = 0; n < 4; n++) {
      const int gr = bm * 128 + wr * 64 + m * 16 + ((lane >> 4) << 2);
      const int gc = bn * 128 + wc * 64 + n * 16 + fr;
#pragma unroll
      for (int r = 0; r < 4; r++)
        C[(size_t)(gr + r) * ncols + gc + blockIdx.z * cstride] = acc[m][n][r];
    }
}

// ---------------------------------------------------------------------------
// Sum 4 split-K partials into the output.  1M floats.
// ---------------------------------------------------------------------------
__global__ __launch_bounds__(256) void reduce4(const float* __restrict__ p,
                                               float* __restrict__ out)
{
  const int i = blockIdx.x * 256 + threadIdx.x;      // float4 index
  const float4* p4 = (const float4*)p;
  const float4 a = p4[i], b = p4[i + 262144], c = p4[i + 524288], d = p4[i + 786432];
  ((float4*)out)[i] = make_float4(a.x + b.x + c.x + d.x, a.y + b.y + c.y + d.y,
                                  a.z + b.z + c.z + d.z, a.w + b.w + c.w + d.w);
}

// ---------------------------------------------------------------------------
// FFT pieces (computed twiddles — round-7/9 validated). ANG0 = -2*pi/1024.
// ---------------------------------------------------------------------------
#define ANG0 (-0.0061359231515425650f)

template<int ST>
__device__ __forceinline__ void fft_mid(const float* __restrict__ sr,
                                        const float* __restrict__ si,
                                        float* __restrict__ dr,
                                        float* __restrict__ di, int tid,
                                        int j0, int j1, int j2, int j3)
{
  const int ls = 2 * ST, s = 1 << ls;
  const int p = tid >> ls, q = tid & (s - 1), tb = tid & ~(s - 1);
  const float a0r = sr[j0], a0i = si[j0], a1r = sr[j1], a1i = si[j1];
  const float a2r = sr[j2], a2i = si[j2], a3r = sr[j3], a3i = si[j3];
  const float b0r = a0r + a2r, b0i = a0i + a2i, b1r = a1r + a3r, b1i = a1i + a3i;
  const float b2r = a0r - a2r, b2i = a0i - a2i, b3r = a1r - a3r, b3i = a1i - a3i;
  const float A0r = b0r + b1r, A0i = b0i + b1i;
  const float A1r = b2r + b3i, A1i = b2i - b3r;
  const float A2r = b0r - b1r, A2i = b0i - b1i;
  const float A3r = b2r - b3i, A3i = b2i + b3r;
  const int o = q + 4 * s * p;
  dr[pad(o)] = A0r; di[pad(o)] = A0i;
  if constexpr (ST < 4) {
    float s1, c1; __sincosf(ANG0 * (float)tb, &s1, &c1);
    const float c2 = c1 * c1 - s1 * s1, s2 = 2.f * s1 * c1;
    const float c3 = c1 * c2 - s1 * s2, s3 = s1 * c2 + c1 * s2;
    dr[pad(o + s)]     = A1r * c1 - A1i * s1; di[pad(o + s)]     = A1r * s1 + A1i * c1;
    dr[pad(o + 2 * s)] = A2r * c2 - A2i * s2; di[pad(o + 2 * s)] = A2r * s2 + A2i * c2;
    dr[pad(o + 3 * s)] = A3r * c3 - A3i * s3; di[pad(o + 3 * s)] = A3r * s3 + A3i * c3;
  } else {
    dr[pad(o + s)]     = A1r; di[pad(o + s)]     = A1i;
    dr[pad(o + 2 * s)] = A2r; di[pad(o + 2 * s)] = A2i;
    dr[pad(o + 3 * s)] = A3r; di[pad(o + 3 * s)] = A3i;
  }
  __syncthreads();
}

// Half-width radix-4 stage of the 512-pt FFT (threads 0..127 active).
template<int J>
__device__ __forceinline__ void fft512_mid(const float* __restrict__ sr,
                                           const float* __restrict__ si,
                                           float* __restrict__ dr,
                                           float* __restrict__ di, int tid)
{
  if (tid < 128) {
    constexpr int s  = (J == 1) ? 2 : (J == 2) ? 8 : 32;
    constexpr int ns = (J == 1) ? 256 : (J == 2) ? 64 : 16;
    constexpr int ls = (J == 1) ? 1 : (J == 2) ? 3 : 5;
    const int p = tid >> ls, q = tid & (s - 1);
    const float a0r = sr[pad(tid)],       a0i = si[pad(tid)];
    const float a1r = sr[pad(tid + 128)], a1i = si[pad(tid + 128)];
    const float a2r = sr[pad(tid + 256)], a2i = si[pad(tid + 256)];
    const float a3r = sr[pad(tid + 384)], a3i = si[pad(tid + 384)];
    const float b0r = a0r + a2r, b0i = a0i + a2i, b1r = a1r + a3r, b1i = a1i + a3i;
    const float b2r = a0r - a2r, b2i = a0i - a2i, b3r = a1r - a3r, b3i = a1i - a3i;
    const float A0r = b0r + b1r, A0i = b0i + b1i;
    const float A1r = b2r + b3i, A1i = b2i - b3r;
    const float A2r = b0r - b1r, A2i = b0i - b1i;
    const float A3r = b2r - b3i, A3i = b2i + b3r;
    float s1, c1; __sincosf((-6.283185307179586f / (float)ns) * (float)p, &s1, &c1);
    const float c2 = c1 * c1 - s1 * s1, s2 = 2.f * s1 * c1;
    const float c3 = c1 * c2 - s1 * s2, s3 = s1 * c2 + c1 * s2;
    const int o = q + 4 * s * p;
    dr[pad(o)]         = A0r;                 di[pad(o)]         = A0i;
    dr[pad(o + s)]     = A1r * c1 - A1i * s1; di[pad(o + s)]     = A1r * s1 + A1i * c1;
    dr[pad(o + 2 * s)] = A2r * c2 - A2i * s2; di[pad(o + 2 * s)] = A2r * s2 + A2i * c2;
    dr[pad(o + 3 * s)] = A3r * c3 - A3i * s3; di[pad(o + 3 * s)] = A3r * s3 + A3i * c3;
  }
  __syncthreads();
}

// ---------------------------------------------------------------------------
// Row pass (1-row/block, round-9/12 validated): softmaxes, gate, FFT1 (1024),
// Hermitian product, irfft via 512, sharpen, normalize.
// ---------------------------------------------------------------------------
__global__ __launch_bounds__(256) void rowpass(
    const __half* __restrict__ slogH, const __half* __restrict__ cosbH,
    const float* __restrict__ bgg, const float* __restrict__ prev,
    float* __restrict__ wout, short* __restrict__ wbf)
{
  __shared__ float bAr[1088], bAi[1088], bBr[1088], bBi[1088];
  __shared__ float sred[8];
  const int b = blockIdx.x, tid = threadIdx.x;
  const int lane = tid & 63, wid = tid >> 6;
  const int j0 = pad(tid), j1 = pad(tid + 256), j2 = pad(tid + 512), j3 = pad(tid + 768);

  const float beta = bgg[b * 4 + 0], g = bgg[b * 4 + 1], gamma = bgg[b * 4 + 2];

  float sv[4], cv[4];
  float e1 = 0.f, e2 = 0.f;
#pragma unroll
  for (int i = 0; i < 4; i++) {
    sv[i] = __expf(__half2float(slogH[(size_t)b * NDIM + tid + i * 256]));
    cv[i] = __expf(beta * __half2float(cosbH[(size_t)b * NDIM + tid + i * 256]));
    e1 += sv[i]; e2 += cv[i];
  }
#pragma unroll
  for (int o = 32; o; o >>= 1) { e1 += __shfl_xor(e1, o); e2 += __shfl_xor(e2, o); }
  if (lane == 0) { sred[wid * 2] = e1; sred[wid * 2 + 1] = e2; }
  __syncthreads();
  const float r1 = 1.f / (sred[0] + sred[2] + sred[4] + sred[6]);
  const float r2 = 1.f / (sred[1] + sred[3] + sred[5] + sred[7]);

  float s1, c1; __sincosf(ANG0 * (float)tid, &s1, &c1);
  const float c2 = c1 * c1 - s1 * s1, s2 = 2.f * s1 * c1;
  const float c3 = c1 * c2 - s1 * s2, s3 = s1 * c2 + c1 * s2;

  // ---- pack + stage 0 of FFT1 in registers -> B ----
  {
    float ar[4], ai[4];
#pragma unroll
    for (int i = 0; i < 4; i++) {
      const int idx = tid + i * 256;
      const float pv = prev[(size_t)b * NDIM + idx];
      ar[i] = g * cv[i] * r2 + (1.f - g) * pv;   // w_g
      ai[i] = sv[i] * r1;                        // s
    }
    const float b0r = ar[0] + ar[2], b0i = ai[0] + ai[2];
    const float b1r = ar[1] + ar[3], b1i = ai[1] + ai[3];
    const float b2r = ar[0] - ar[2], b2i = ai[0] - ai[2];
    const float b3r = ar[1] - ar[3], b3i = ai[1] - ai[3];
    const float A0r = b0r + b1r, A0i = b0i + b1i;
    const float A1r = b2r + b3i, A1i = b2i - b3r;
    const float A2r = b0r - b1r, A2i = b0i - b1i;
    const float A3r = b2r - b3i, A3i = b2i + b3r;
    const int o4 = 4 * tid;
    bBr[pad(o4)]     = A0r;                  bBi[pad(o4)]     = A0i;
    bBr[pad(o4 + 1)] = A1r * c1 - A1i * s1;  bBi[pad(o4 + 1)] = A1r * s1 + A1i * c1;
    bBr[pad(o4 + 2)] = A2r * c2 - A2i * s2;  bBi[pad(o4 + 2)] = A2r * s2 + A2i * c2;
    bBr[pad(o4 + 3)] = A3r * c3 - A3i * s3;  bBi[pad(o4 + 3)] = A3r * s3 + A3i * c3;
  }
  __syncthreads();

  fft_mid<1>(bBr, bBi, bAr, bAi, tid, j0, j1, j2, j3);
  fft_mid<2>(bAr, bAi, bBr, bBi, tid, j0, j1, j2, j3);
  fft_mid<3>(bBr, bBi, bAr, bAi, tid, j0, j1, j2, j3);
  fft_mid<4>(bAr, bAi, bBr, bBi, tid, j0, j1, j2, j3);   // Z in B, natural order

  // ---- Hermitian product: P[k] = W[k]*S[k], k = 0..512 -> A ----
#pragma unroll
  for (int i = 0; i < 2; i++) {
    const int k = tid + i * 256;
    const int kp = pad(k), rp = pad((1024 - k) & 1023);
    const float Zkr = bBr[kp], Zki = bBi[kp];
    const float Zrr = bBr[rp], Zri = bBi[rp];
    const float Wr = 0.5f * (Zkr + Zrr), Wi = 0.5f * (Zki - Zri);
    const float Sr = 0.5f * (Zki + Zri), Si = 0.5f * (Zrr - Zkr);
    bAr[kp] = Wr * Sr - Wi * Si;
    bAi[kp] = Wr * Si + Wi * Sr;
  }
  if (tid == 0) {
    const int kp = pad(512);
    bAr[kp] = bBr[kp] * bBi[kp];   // W=Re(Z512), S=Im(Z512), both real
    bAi[kp] = 0.f;
  }
  __syncthreads();

  // ---- Q construction + conj + radix-2 register stage -> B (512 pts) ----
  {
    float es, ec; __sincosf(0.0061359231515425650f * (float)tid, &es, &ec);
    const float P0r = bAr[pad(tid)],        P0i = bAi[pad(tid)];
    const float Pa0r = bAr[pad(512 - tid)], Pa0i = bAi[pad(512 - tid)];
    const float S0r = P0r + Pa0r, S0i = P0i - Pa0i;
    const float D0r = P0r - Pa0r, D0i = P0i + Pa0i;
    const float Q0r = S0r - es * D0r - ec * D0i;
    const float Q0i = S0i + ec * D0r - es * D0i;
    const float P1r = bAr[pad(tid + 256)],  P1i = bAi[pad(tid + 256)];
    const float Pa1r = bAr[pad(256 - tid)], Pa1i = bAi[pad(256 - tid)];
    const float S1r = P1r + Pa1r, S1i = P1i - Pa1i;
    const float D1r = P1r - Pa1r, D1i = P1i + Pa1i;
    const float Q1r = S1r - ec * D1r + es * D1i;
    const float Q1i = S1i - es * D1r - ec * D1i;
    const float ur = Q0r, ui = -Q0i, vr = Q1r, vi = -Q1i;
    float ts, tc; __sincosf(-0.012271846303085130f * (float)tid, &ts, &tc);
    const float d_r = ur - vr, d_i = ui - vi;
    bBr[pad(2 * tid)]     = ur + vr;             bBi[pad(2 * tid)]     = ui + vi;
    bBr[pad(2 * tid + 1)] = d_r * tc - d_i * ts; bBi[pad(2 * tid + 1)] = d_r * ts + d_i * tc;
  }
  __syncthreads();

  fft512_mid<1>(bBr, bBi, bAr, bAi, tid);
  fft512_mid<2>(bAr, bAi, bBr, bBi, tid);
  fft512_mid<3>(bBr, bBi, bAr, bAi, tid);

  if (tid < 128) {
    const int i0 = pad(tid), i1 = pad(tid + 128), i2 = pad(tid + 256), i3 = pad(tid + 384);
    const float a0r = bAr[i0], a0i = bAi[i0], a1r = bAr[i1], a1i = bAi[i1];
    const float a2r = bAr[i2], a2i = bAi[i2], a3r = bAr[i3], a3i = bAi[i3];
    const float b0r = a0r + a2r, b0i = a0i + a2i, b1r = a1r + a3r, b1i = a1i + a3i;
    const float b2r = a0r - a2r, b2i = a0i - a2i, b3r = a1r - a3r, b3i = a1i - a3i;
    bBr[i0] = b0r + b1r; bBi[i0] = b0i + b1i;
    bBr[i1] = b2r + b3i; bBi[i1] = b2i - b3r;
    bBr[i2] = b0r - b1r; bBi[i2] = b0i - b1i;
    bBr[i3] = b2r - b3i; bBi[i3] = b2i + b3r;
  }
  __syncthreads();

  const int m0 = pad(2 * tid), m1 = pad(2 * tid + 1);
  float xv[4];
  xv[0] =  bBr[m0] * (1.f / 1024.f);
  xv[1] = -bBi[m0] * (1.f / 1024.f);
  xv[2] =  bBr[m1] * (1.f / 1024.f);
  xv[3] = -bBi[m1] * (1.f / 1024.f);

  float wt[4]; float esum = 0.f;
#pragma unroll
  for (int i = 0; i < 4; i++) {
    const float v = fmaxf(xv[i], 0.f);
    const float p = (v > 0.f) ? __expf(gamma * __logf(v)) : 0.f;
    wt[i] = p; esum += p;
  }
#pragma unroll
  for (int o = 32; o; o >>= 1) esum += __shfl_xor(esum, o);
  if (lane == 0) sred[wid] = esum;
  __syncthreads();
  const float rn = 1.f / (sred[0] + sred[1] + sred[2] + sred[3] + 1e-16f);
  const float w0 = wt[0] * rn, w1 = wt[1] * rn, w2 = wt[2] * rn, w3 = wt[3] * rn;
  *(float4*)(wout + (size_t)b * NDIM + 4 * tid) = make_float4(w0, w1, w2, w3);
  short4v wb;
  wb[0] = (short)f2bfu(w0); wb[1] = (short)f2bfu(w1);
  wb[2] = (short)f2bfu(w2); wb[3] = (short)f2bfu(w3);
  *(short4v*)(wbf + (size_t)b * NDIM + 4 * tid) = wb;
}

// ---------------------------------------------------------------------------
extern "C" void kernel_launch(void* const* d_in, const int* in_sizes, int n_in,
                              void* d_out, int out_size, void* d_ws, size_t ws_size,
                              hipStream_t stream)
{
  const float* x    = (const float*)d_in[0];
  const float* prev = (const float*)d_in[1];
  const float* mem  = (const float*)d_in[2];
  const float* Wk   = (const float*)d_in[3];
  const float* bk   = (const float*)d_in[4];
  const float* Wb   = (const float*)d_in[5];
  const float* bb   = (const float*)d_in[6];
  const float* Wg   = (const float*)d_in[7];
  const float* bg   = (const float*)d_in[8];
  const float* Ws   = (const float*)d_in[9];
  const float* bs   = (const float*)d_in[10];
  const float* Wgam = (const float*)d_in[11];
  const float* bgam = (const float*)d_in[12];

  char* ws = (char*)d_ws;
  short*  mn_bf   = (short*) (ws + 0);          //  256 KB
  short*  memT_bf = (short*) (ws + 262144);     //  256 KB
  float*  bgg     = (float*) (ws + 524288);     //  128 KB
  __half* slogH   = (__half*)(ws + 655360);     //   16 MB
  __half* cosbH   = (__half*)(ws + 17432576);   //   16 MB
  short*  xb      = (short*) (ws + 34209792);   //    8 MB
  short*  wsb     = (short*) (ws + 42598400);   //    1 MB
  short*  wkb     = (short*) (ws + 43646976);   //  128 KB
  short*  wbf     = (short*) (ws + 43778048);   //   16 MB
  float*  rpart   = (float*) (ws + 60555264);   //   16 MB (ends ~77.3 MB)

  float* readout = (float*)d_out;                  // [8192][128]
  float* wout = readout + (size_t)B_ROWS * MDIM;   // [8192][1024]

  prep_all<<<2704, 256, 0, stream>>>(x, Ws, Wk, mem, Wb, bb, Wg, bg, Wgam, bgam,
                                     xb, wsb, wkb, mn_bf, memT_bf, bgg);
  heads<<<768, 256, 0, stream>>>(xb, wkb, bk, mn_bf, cosbH, wsb, bs, slogH);
  rowpass<<<B_ROWS, 256, 0, stream>>>(slogH, cosbH, bgg, prev, wout, wbf);
  kgemm_read<<<dim3(1, B_ROWS / 128, 4), 256, 0, stream>>>(
      wbf, memT_bf, rpart, MDIM, NDIM, 256, (size_t)B_ROWS * MDIM);
  reduce4<<<1024, 256, 0, stream>>>(rpart, readout);
}